// Round 20
// baseline (1127.035 us; speedup 1.0000x reference)
//
#include <hip/hip_runtime.h>

// Problem constants
#define NBATCH 16
#define WEMB   512
#define TLEN   8192
#define KBINS  2048
#define NTROWS (NBATCH * TLEN)                       // 131072
#define XQN    (NBATCH * WEMB * TLEN)                // 67108864
#define XQ_OFF ((size_t)NTROWS)
#define SC_OFF ((size_t)NTROWS + (size_t)XQN)

#define FIX_CAP  65536
#define FIX2_CAP 8192
#define MARGIN1  0.2f     // fp16 pass flag threshold (~9 sigma)
#define MARGIN2  0.02f    // bf16-3prod pass flag threshold (~20 sigma)

#define R      64
#define XS_ROW 512    // fp16 elems per x_s row in pass 1

typedef _Float16 half8 __attribute__((ext_vector_type(8)));
typedef __attribute__((ext_vector_type(8)))  short short8;
typedef __attribute__((ext_vector_type(4)))  float f32x4;
typedef __attribute__((ext_vector_type(16))) float f32x16;

// Module-scope scratch; fully rewritten every launch.
__device__ float          g_k2[KBINS];
__device__ double         g_fitp[2048];
__device__ double         g_pnp[2 * 2048];
__device__ int            g_idx[NTROWS];
__device__ int            g_list[FIX_CAP];
__device__ int            g_nfix;
__device__ int            g_list2[FIX2_CAP];
__device__ int            g_nfix2;
__device__ unsigned short g_kh[KBINS * WEMB];        // fp16 plane of k (2 MB)
__device__ unsigned short g_kbh[KBINS * WEMB];       // bf16 hi plane (2 MB)
__device__ unsigned short g_kbl[KBINS * WEMB];       // bf16 lo plane (2 MB)

static __device__ __forceinline__ unsigned short f2h(float f) {
  _Float16 h = (_Float16)f;
  unsigned short u;
  __builtin_memcpy(&u, &h, 2);
  return u;
}
static __device__ __forceinline__ unsigned short f2bf(float f) {
  unsigned int u;
  __builtin_memcpy(&u, &f, 4);
  return (unsigned short)((u + 0x7FFFu + ((u >> 16) & 1u)) >> 16);
}
static __device__ __forceinline__ float bf2f(unsigned short h) {
  unsigned int u = ((unsigned int)h) << 16;
  float f;
  __builtin_memcpy(&f, &u, 4);
  return f;
}

__global__ void zero_kernel() { g_nfix = 0; g_nfix2 = 0; }

// ---------------------------------------------------------------- k2[c] = sum_w k[c][w]^2
__global__ __launch_bounds__(256) void k2_kernel(const float* __restrict__ k) {
  const int c = blockIdx.x * 4 + (threadIdx.x >> 6);
  const int lane = threadIdx.x & 63;
  const float4* kr = (const float4*)(k + (size_t)c * WEMB);
  float s = 0.f;
#pragma unroll
  for (int i = 0; i < 2; ++i) {
    float4 v = kr[lane + 64 * i];
    s += v.x * v.x + v.y * v.y + v.z * v.z + v.w * v.w;
  }
#pragma unroll
  for (int m = 1; m < 64; m <<= 1) s += __shfl_xor(s, m);
  if (lane == 0) g_k2[c] = s;
}

// ---------------------------------------------------------------- k -> fp16 + bf16 hi/lo
__global__ __launch_bounds__(256) void kprep_kernel(const float* __restrict__ k) {
  const int i = blockIdx.x * 256 + threadIdx.x;    // over 262144 float4
  float4 v = ((const float4*)k)[i];
  ushort4 hf, hb, lb;
  hf.x = f2h(v.x); hb.x = f2bf(v.x); lb.x = f2bf(v.x - bf2f(hb.x));
  hf.y = f2h(v.y); hb.y = f2bf(v.y); lb.y = f2bf(v.y - bf2f(hb.y));
  hf.z = f2h(v.z); hb.z = f2bf(v.z); lb.z = f2bf(v.z - bf2f(hb.z));
  hf.w = f2h(v.w); hb.w = f2bf(v.w); lb.w = f2bf(v.w - bf2f(hb.w));
  ((ushort4*)g_kh)[i]  = hf;
  ((ushort4*)g_kbh)[i] = hb;
  ((ushort4*)g_kbl)[i] = lb;
}

// ---------------------------------------------------------------- pass 1: fp16 VQ kernel
// 32x32x16 MFMA, swapped operands: A=k (32 codes, global), B=x (32 rows, LDS).
// Halves LDS B-traffic per flop vs 16x16x32. Lane holds 16 codes x 1 row per tile;
// in-lane top-2 + single xor-32 butterfly; running state in wave-private LDS.
#define EPIL32(ACC, TILE)                                                        \
  { const int row = (TILE) * 32 + c32;                                           \
    const float xx = x2s[row];                                                   \
    float e1 = 3.4e38f, e2 = 3.4e38f; int ei = 0x7FFFFFFF;                       \
    _Pragma("unroll")                                                            \
    for (int q = 0; q < 4; ++q) {                                                \
      const float4 kq = *(const float4*)&g_k2[cb + 8 * q + 4 * hi];              \
      _Pragma("unroll")                                                          \
      for (int e = 0; e < 4; ++e) {                                              \
        const float kv = (e == 0) ? kq.x : (e == 1) ? kq.y : (e == 2) ? kq.z : kq.w; \
        const float d = fmaf(-2.f, ACC[4 * q + e], xx) + kv;                     \
        const int code = cb + 8 * q + 4 * hi + e;      /* ascending per lane */  \
        if (d < e1) { e2 = e1; e1 = d; ei = code; } else e2 = fminf(e2, d);      \
      }                                                                          \
    }                                                                            \
    { const float o1 = __shfl_xor(e1, 32);                                       \
      const float o2 = __shfl_xor(e2, 32);                                       \
      const int   oi = __shfl_xor(ei, 32);                                       \
      if (o1 < e1)      { e2 = fminf(e1, o2); e1 = o1; ei = oi; }                \
      else if (o1 > e1) { e2 = fminf(e2, o1); }                                  \
      else              { e2 = fminf(e2, o2); if (oi < ei) ei = oi; }            \
    }                                                                            \
    if (hi == 0) {       /* wave-private LDS merge, no barrier needed */         \
      const float c1 = cand_d1[wv][row], c2 = cand_d2[wv][row];                  \
      const int ci = cand_i[wv][row];                                            \
      if (e1 < c1)      { cand_d2[wv][row] = fminf(c1, e2); cand_d1[wv][row] = e1; cand_i[wv][row] = ei; } \
      else if (e1 > c1) { cand_d2[wv][row] = fminf(c2, e1); }                    \
      else              { cand_d2[wv][row] = fminf(c2, e2); if (ei < ci) cand_i[wv][row] = ei; } \
    } }

__global__ __launch_bounds__(1024, 8) void vq_mfma(const float* __restrict__ x) {
  __shared__ unsigned short x_s[R * XS_ROW];   // 65536 B, fp16, swizzled
  __shared__ float  cand_d1[16][R];            // doubles as px2 during staging
  __shared__ float  cand_d2[16][R];
  __shared__ int    cand_i[16][R];
  __shared__ float  x2s[R];
  __shared__ double pnred[32];

  const int tid = threadIdx.x;
  const int wv = tid >> 6, lane = tid & 63;
  const int c32 = lane & 31, hi = lane >> 5;
  const int rows0 = blockIdx.x * R;
  const int n = rows0 >> 13, t0 = rows0 & (TLEN - 1);
  const int swz32 = (c32 & 7) << 3;

  // ---- staging: transpose + fp16 convert + x2 + prenorm (f32 partials) ----
  {
    float sv = 0.f, px = 0.f;
    const size_t xb = ((size_t)(n * WEMB + wv * 32)) * TLEN + (size_t)(t0 + lane);
    const int wsz = (lane & 7) << 3;
#pragma unroll
    for (int jg = 0; jg < 4; ++jg) {
      half8 h8;
#pragma unroll
      for (int j = 0; j < 8; ++j) {
        const float v = __builtin_nontemporal_load(&x[xb + (size_t)(jg * 8 + j) * TLEN]);
        h8[j] = (_Float16)v;
        px = fmaf(v, v, px);
        sv += v;
      }
      const int col = wv * 32 + jg * 8;
      *(half8*)&x_s[lane * XS_ROW + (col ^ wsz)] = h8;
    }
    cand_d1[wv][lane] = px;     // per-lane x2 slice
    float svr = sv, pxr = px;
#pragma unroll
    for (int m = 1; m < 64; m <<= 1) { svr += __shfl_xor(svr, m); pxr += __shfl_xor(pxr, m); }
    if (lane == 0) { pnred[wv] = (double)svr; pnred[16 + wv] = (double)pxr; }
  }
  __syncthreads();
  if (tid < R) {
    float t = 0.f;
#pragma unroll
    for (int w16 = 0; w16 < 16; ++w16) t += cand_d1[w16][tid];
    x2s[tid] = t;
  }
  if (tid == 0) {
    double a = 0, b = 0;
#pragma unroll
    for (int w16 = 0; w16 < 16; ++w16) { a += pnred[w16]; b += pnred[16 + w16]; }
    g_pnp[2 * blockIdx.x] = a; g_pnp[2 * blockIdx.x + 1] = b;
  }
  __syncthreads();

  // ---- init wave-private running top-2 state ----
  cand_d1[wv][lane] = 3.4e38f;
  cand_d2[wv][lane] = 3.4e38f;
  cand_i [wv][lane] = 0x7FFFFFFF;

  // ---- main loop: 4 chunks x 512 codes; wave strip = 32 codes; barrier-free ----
  for (int cc = 0; cc < 4; ++cc) {
    const int cb = cc * 512 + wv * 32;
    const unsigned short* kp = g_kh + ((size_t)(cb + c32)) * WEMB + (size_t)(hi * 8);
    f32x16 acc0, acc1;
#pragma unroll
    for (int i = 0; i < 16; ++i) { acc0[i] = 0.f; acc1[i] = 0.f; }

#pragma unroll 1
    for (int ks = 0; ks < 32; ++ks) {   // K-step 16
      const half8 ak  = *(const half8*)&kp[ks * 16];
      const int   col = (ks * 16 + hi * 8) ^ swz32;
      const half8 bx0 = *(const half8*)&x_s[c32 * XS_ROW + col];
      const half8 bx1 = *(const half8*)&x_s[(32 + c32) * XS_ROW + col];
      acc0 = __builtin_amdgcn_mfma_f32_32x32x16_f16(ak, bx0, acc0, 0, 0, 0);
      acc1 = __builtin_amdgcn_mfma_f32_32x32x16_f16(ak, bx1, acc1, 0, 0, 0);
    }
    EPIL32(acc0, 0)
    EPIL32(acc1, 1)
  }

  // ---- final cross-wave merge ----
  __syncthreads();
  if (tid < R) {
    float m1 = 3.4e38f, m2 = 3.4e38f; int mi = 0x7FFFFFFF;
#pragma unroll
    for (int w16 = 0; w16 < 16; ++w16) {
      const float c1 = cand_d1[w16][tid], c2 = cand_d2[w16][tid];
      const int ci = cand_i[w16][tid];
      if (c1 < m1)      { m2 = fminf(m1, c2); m1 = c1; mi = ci; }
      else if (c1 > m1) { m2 = fminf(m2, c1); }
      else              { m2 = fminf(m2, c2); if (ci < mi) mi = ci; }
    }
    const int grow = rows0 + tid;
    g_idx[grow] = mi;
    if (m2 - m1 < MARGIN1) {
      const int pos = atomicAdd(&g_nfix, 1);
      if (pos < FIX_CAP) g_list[pos] = grow;
    }
    double fs = (double)m1;
#pragma unroll
    for (int m = 1; m < 64; m <<= 1) fs += __shfl_xor(fs, m);
    if (tid == 0) g_fitp[blockIdx.x] = fs;
  }
}

// ---------------------------------------------------------------- pass 2: bf16-3prod rescan of flagged rows
__global__ __launch_bounds__(1024, 1) void fix1_mfma(const float* __restrict__ x) {
  __shared__ short  x_s[64 * 1024];        // 128 KB bf16 hi/lo, swizzled
  __shared__ float  cand_d1[16][64];
  __shared__ float  cand_d2[16][64];
  __shared__ int    cand_i[16][64];
  __shared__ float  x2s[64];
  __shared__ float  rd1[64], rd2[64];
  __shared__ int    ri1[64];

  const int tid = threadIdx.x;
  const int wv = tid >> 6, lane = tid & 63;
  const int g = lane >> 4, i16 = lane & 15;
  const int swz = (i16 & 7) << 3;
  const int nfix = g_nfix < FIX_CAP ? g_nfix : FIX_CAP;

  for (int base = blockIdx.x * 64; base < nfix; base += gridDim.x * 64) {
    __syncthreads();
    if (tid < 64) { rd1[tid] = 3.4e38f; rd2[tid] = 3.4e38f; ri1[tid] = 0; }
    {
      const int rl = tid >> 4;
      int e = base + rl; if (e >= nfix) e = nfix - 1;
      const int row = g_list[e];
      const int n = row >> 13, t = row & (TLEN - 1);
      const int ks = tid & 15;
      const int wsz = (rl & 7) << 3;
      float px = 0.f;
#pragma unroll
      for (int jg = 0; jg < 4; ++jg) {
        short8 h8, l8;
#pragma unroll
        for (int j = 0; j < 8; ++j) {
          const int w = ks * 32 + jg * 8 + j;
          const float v = x[((size_t)(n * WEMB + w)) * TLEN + (size_t)t];
          const unsigned short h = f2bf(v);
          const unsigned short lo = f2bf(v - bf2f(h));
          h8[j] = (short)h; l8[j] = (short)lo;
          px = fmaf(v, v, px);
        }
        const int colh = ks * 64 + jg * 8;
        *(short8*)&x_s[rl * 1024 + (colh ^ wsz)] = h8;
        *(short8*)&x_s[rl * 1024 + ((colh + 32) ^ wsz)] = l8;
      }
#pragma unroll
      for (int m = 1; m < 16; m <<= 1) px += __shfl_xor(px, m);
      if (ks == 0) x2s[rl] = px;
    }
    __syncthreads();

    for (int cc = 0; cc < 4; ++cc) {
      const int cb = cc * 512 + wv * 32;
      f32x4 acc[4][2];
#pragma unroll
      for (int mt = 0; mt < 4; ++mt)
#pragma unroll
        for (int nt = 0; nt < 2; ++nt) acc[mt][nt] = (f32x4){0.f, 0.f, 0.f, 0.f};

#pragma unroll 1
      for (int ks = 0; ks < 16; ++ks) {
        short8 bh[2], bl[2];
#pragma unroll
        for (int nt = 0; nt < 2; ++nt) {
          const size_t bidx = ((size_t)(cb + nt * 16 + i16)) * WEMB + (size_t)(ks * 32 + g * 8);
          bh[nt] = *(const short8*)&g_kbh[bidx];
          bl[nt] = *(const short8*)&g_kbl[bidx];
        }
#pragma unroll
        for (int mt = 0; mt < 4; ++mt) {
          const int rbase = (mt * 16 + i16) * 1024 + (ks * 64);
          const short8 ah = *(const short8*)&x_s[rbase + ((g * 8) ^ swz)];
          const short8 al = *(const short8*)&x_s[rbase + ((32 + g * 8) ^ swz)];
          acc[mt][0] = __builtin_amdgcn_mfma_f32_16x16x32_bf16(ah, bh[0], acc[mt][0], 0, 0, 0);
          acc[mt][1] = __builtin_amdgcn_mfma_f32_16x16x32_bf16(ah, bh[1], acc[mt][1], 0, 0, 0);
          acc[mt][0] = __builtin_amdgcn_mfma_f32_16x16x32_bf16(ah, bl[0], acc[mt][0], 0, 0, 0);
          acc[mt][1] = __builtin_amdgcn_mfma_f32_16x16x32_bf16(ah, bl[1], acc[mt][1], 0, 0, 0);
          acc[mt][0] = __builtin_amdgcn_mfma_f32_16x16x32_bf16(al, bh[0], acc[mt][0], 0, 0, 0);
          acc[mt][1] = __builtin_amdgcn_mfma_f32_16x16x32_bf16(al, bh[1], acc[mt][1], 0, 0, 0);
        }
      }

      float k2v[2];
#pragma unroll
      for (int nt = 0; nt < 2; ++nt) k2v[nt] = g_k2[cb + nt * 16 + i16];
#pragma unroll
      for (int mt = 0; mt < 4; ++mt) {
#pragma unroll
        for (int rr = 0; rr < 4; ++rr) {
          const int row = mt * 16 + g * 4 + rr;
          const float xx = x2s[row];
          float e1 = 3.4e38f, e2 = 3.4e38f; int ei = 0x7FFFFFFF;
#pragma unroll
          for (int nt = 0; nt < 2; ++nt) {
            const float d = fmaf(-2.f, acc[mt][nt][rr], xx) + k2v[nt];
            const int code = cb + nt * 16 + i16;
            if (d < e1) { e2 = e1; e1 = d; ei = code; } else e2 = fminf(e2, d);
          }
#pragma unroll
          for (int m = 1; m < 16; m <<= 1) {
            const float o1 = __shfl_xor(e1, m);
            const float o2 = __shfl_xor(e2, m);
            const int   oi = __shfl_xor(ei, m);
            if (o1 < e1)      { e2 = fminf(e1, o2); e1 = o1; ei = oi; }
            else if (o1 > e1) { e2 = fminf(e2, o1); }
            else              { e2 = e1; if (oi < ei) ei = oi; }
          }
          if (i16 == 0) { cand_d1[wv][row] = e1; cand_d2[wv][row] = e2; cand_i[wv][row] = ei; }
        }
      }
      __syncthreads();
      if (tid < 64) {
        float m1 = rd1[tid], m2 = rd2[tid]; int mi = ri1[tid];
#pragma unroll
        for (int w16 = 0; w16 < 16; ++w16) {
          const float c1 = cand_d1[w16][tid], c2 = cand_d2[w16][tid];
          const int ci = cand_i[w16][tid];
          if (c1 < m1)      { m2 = fminf(m1, c2); m1 = c1; mi = ci; }
          else if (c1 > m1) { m2 = fminf(m2, c1); }
          else              { m2 = fminf(m2, c2); if (ci < mi) mi = ci; }
        }
        rd1[tid] = m1; rd2[tid] = m2; ri1[tid] = mi;
      }
      __syncthreads();
    }

    if (tid < 64) {
      const int e = base + tid;
      if (e < nfix) {
        const int row = g_list[e];
        g_idx[row] = ri1[tid];
        if (rd2[tid] - rd1[tid] < MARGIN2) {
          const int p = atomicAdd(&g_nfix2, 1);
          if (p < FIX2_CAP) g_list2[p] = row;
        }
      }
    }
  }
}

// ---------------------------------------------------------------- pass 3: exact f64 scan of list2
__global__ __launch_bounds__(256) void fix2_kernel(const float* __restrict__ x,
                                                   const float* __restrict__ k) {
  __shared__ float  xr[WEMB];
  __shared__ double rbd[4];
  __shared__ int    rbi[4];
  const int nf = g_nfix2 < FIX2_CAP ? g_nfix2 : FIX2_CAP;
  const int tid = threadIdx.x, lane = tid & 63, wv = tid >> 6;
  for (int e = blockIdx.x; e < nf; e += gridDim.x) {
    const int row = g_list2[e];
    const int n = row >> 13, t = row & (TLEN - 1);
    for (int w = tid; w < WEMB; w += 256)
      xr[w] = x[(size_t)(n * WEMB + w) * TLEN + (size_t)t];
    __syncthreads();
    double bd = 1e300; int bi = 0x7FFFFFFF;
    for (int p = 0; p < 8; ++p) {
      const int c = tid + 256 * p;
      const float* kc = k + (size_t)c * WEMB;
      double d = 0.0;
      for (int w = 0; w < WEMB; ++w) {
        const double df = (double)xr[w] - (double)kc[w];
        d = fma(df, df, d);
      }
      if (d < bd || (d == bd && c < bi)) { bd = d; bi = c; }
    }
#pragma unroll
    for (int m = 1; m < 64; m <<= 1) {
      const double od = __shfl_xor(bd, m);
      const int    oi = __shfl_xor(bi, m);
      if (od < bd || (od == bd && oi < bi)) { bd = od; bi = oi; }
    }
    if (lane == 0) { rbd[wv] = bd; rbi[wv] = bi; }
    __syncthreads();
    if (tid == 0) {
      double fb = rbd[0]; int fi = rbi[0];
#pragma unroll
      for (int v = 1; v < 4; ++v)
        if (rbd[v] < fb || (rbd[v] == fb && rbi[v] < fi)) { fb = rbd[v]; fi = rbi[v]; }
      g_idx[row] = fi;
    }
    __syncthreads();
  }
}

// ---------------------------------------------------------------- x_l write (f32, NT)
__global__ __launch_bounds__(256) void xl_kernel(float* __restrict__ out) {
  const int i = blockIdx.x * 256 + threadIdx.x;
  if (i < NTROWS) __builtin_nontemporal_store((float)g_idx[i], &out[i]);
}

// ---------------------------------------------------------------- x_q write (LDS transpose, NT stores)
__global__ __launch_bounds__(256) void xq_kernel(const float* __restrict__ k,
                                                 float* __restrict__ out) {
  __shared__ float tile[64][257];
  __shared__ int idxs[64];
  const int tb = blockIdx.x;
  const int n = tb >> 7, t0 = (tb & 127) << 6;
  const int tid = threadIdx.x, lane = tid & 63;
  if (tid < 64) idxs[tid] = g_idx[n * TLEN + t0 + tid];
  __syncthreads();
  for (int half = 0; half < 2; ++half) {
    const int w0 = half * 256;
    if (half) __syncthreads();
#pragma unroll 4
    for (int it = 0; it < 16; ++it) {
      const int r = (tid >> 6) + 4 * it;
      const float4 v = *(const float4*)&k[(size_t)idxs[r] * WEMB + (size_t)(w0 + lane * 4)];
      tile[r][lane * 4 + 0] = v.x; tile[r][lane * 4 + 1] = v.y;
      tile[r][lane * 4 + 2] = v.z; tile[r][lane * 4 + 3] = v.w;
    }
    __syncthreads();
#pragma unroll 4
    for (int it = 0; it < 64; ++it) {
      const int wl = it * 4 + (tid >> 6);
      __builtin_nontemporal_store(tile[lane][wl],
          &out[XQ_OFF + ((size_t)(n * WEMB + w0 + wl)) * TLEN + (size_t)(t0 + lane)]);
    }
  }
}

// ---------------------------------------------------------------- final scalars (f32)
__global__ __launch_bounds__(256) void fin_kernel(float* __restrict__ out) {
  const int tid = threadIdx.x;
  double fs = 0, s = 0, s2 = 0;
  for (int i = tid; i < 2048; i += 256) {
    fs += g_fitp[i];
    s  += g_pnp[2 * i];
    s2 += g_pnp[2 * i + 1];
  }
#pragma unroll
  for (int m = 1; m < 64; m <<= 1) {
    fs += __shfl_xor(fs, m); s += __shfl_xor(s, m); s2 += __shfl_xor(s2, m);
  }
  __shared__ double red[12];
  const int wv = tid >> 6, lane = tid & 63;
  if (lane == 0) { red[wv] = fs; red[4 + wv] = s; red[8 + wv] = s2; }
  __syncthreads();
  if (tid == 0) {
    const double F  = red[0] + red[1] + red[2] + red[3];
    const double S  = red[4] + red[5] + red[6] + red[7];
    const double S2 = red[8] + red[9] + red[10] + red[11];
    const double nel = (double)NTROWS * (double)WEMB;
    const double mean = S / nel;
    double var = S2 / nel - mean * mean;
    if (var < 0) var = 0;
    out[SC_OFF + 0] = (float)(F / nel);      // commit_loss
    out[SC_OFF + 1] = (float)(F / NTROWS);   // fit
    out[SC_OFF + 2] = (float)sqrt(var);      // prenorm
  }
}

extern "C" void kernel_launch(void* const* d_in, const int* in_sizes, int n_in,
                              void* d_out, int out_size, void* d_ws, size_t ws_size,
                              hipStream_t stream) {
  const float* x = (const float*)d_in[0];
  const float* k = (const float*)d_in[1];
  float* out = (float*)d_out;
  (void)d_ws; (void)ws_size; (void)in_sizes; (void)n_in; (void)out_size;

  hipLaunchKernelGGL(zero_kernel, dim3(1), dim3(1), 0, stream);
  hipLaunchKernelGGL(k2_kernel, dim3(KBINS / 4), dim3(256), 0, stream, k);
  hipLaunchKernelGGL(kprep_kernel, dim3(1024), dim3(256), 0, stream, k);
  hipLaunchKernelGGL(vq_mfma, dim3(NTROWS / R), dim3(1024), 0, stream, x);
  hipLaunchKernelGGL(fix1_mfma, dim3(512), dim3(1024), 0, stream, x);
  hipLaunchKernelGGL(fix2_kernel, dim3(1024), dim3(256), 0, stream, x, k);
  hipLaunchKernelGGL(xl_kernel, dim3(NTROWS / 256), dim3(256), 0, stream, out);
  hipLaunchKernelGGL(xq_kernel, dim3(2048), dim3(256), 0, stream, k, out);
  hipLaunchKernelGGL(fin_kernel, dim3(1), dim3(256), 0, stream, out);
}

// Round 21
// 935.698 us; speedup vs baseline: 1.2045x; 1.2045x over previous
//
#include <hip/hip_runtime.h>

// Problem constants
#define NBATCH 16
#define WEMB   512
#define TLEN   8192
#define KBINS  2048
#define NTROWS (NBATCH * TLEN)                       // 131072
#define XQN    (NBATCH * WEMB * TLEN)                // 67108864
#define XQ_OFF ((size_t)NTROWS)
#define SC_OFF ((size_t)NTROWS + (size_t)XQN)

#define FIX_CAP  65536
#define FIX2_CAP 8192
#define MARGIN1  0.2f     // fp16 pass flag threshold (~9 sigma)
#define MARGIN2  0.02f    // bf16-3prod pass flag threshold (~20 sigma)

#define R      64
#define XS_ROW 512    // fp16 elems per x_s row in pass 1

typedef _Float16 half8 __attribute__((ext_vector_type(8)));
typedef __attribute__((ext_vector_type(8))) short short8;
typedef __attribute__((ext_vector_type(4))) float f32x4;

// Module-scope scratch; fully rewritten every launch.
__device__ float          g_k2[KBINS];
__device__ double         g_fitp[2048];
__device__ double         g_pnp[2 * 2048];
__device__ int            g_idx[NTROWS];
__device__ int            g_list[FIX_CAP];
__device__ int            g_nfix;
__device__ int            g_list2[FIX2_CAP];
__device__ int            g_nfix2;
__device__ unsigned short g_kh[KBINS * WEMB];        // fp16 plane of k (2 MB)
__device__ unsigned short g_kbh[KBINS * WEMB];       // bf16 hi plane (2 MB)
__device__ unsigned short g_kbl[KBINS * WEMB];       // bf16 lo plane (2 MB)

static __device__ __forceinline__ unsigned short f2h(float f) {
  _Float16 h = (_Float16)f;
  unsigned short u;
  __builtin_memcpy(&u, &h, 2);
  return u;
}
static __device__ __forceinline__ unsigned short f2bf(float f) {
  unsigned int u;
  __builtin_memcpy(&u, &f, 4);
  return (unsigned short)((u + 0x7FFFu + ((u >> 16) & 1u)) >> 16);
}
static __device__ __forceinline__ float bf2f(unsigned short h) {
  unsigned int u = ((unsigned int)h) << 16;
  float f;
  __builtin_memcpy(&f, &u, 4);
  return f;
}

__global__ void zero_kernel() { g_nfix = 0; g_nfix2 = 0; }

// ---------------------------------------------------------------- k2[c] = sum_w k[c][w]^2
__global__ __launch_bounds__(256) void k2_kernel(const float* __restrict__ k) {
  const int c = blockIdx.x * 4 + (threadIdx.x >> 6);
  const int lane = threadIdx.x & 63;
  const float4* kr = (const float4*)(k + (size_t)c * WEMB);
  float s = 0.f;
#pragma unroll
  for (int i = 0; i < 2; ++i) {
    float4 v = kr[lane + 64 * i];
    s += v.x * v.x + v.y * v.y + v.z * v.z + v.w * v.w;
  }
#pragma unroll
  for (int m = 1; m < 64; m <<= 1) s += __shfl_xor(s, m);
  if (lane == 0) g_k2[c] = s;
}

// ---------------------------------------------------------------- k -> fp16 + bf16 hi/lo
__global__ __launch_bounds__(256) void kprep_kernel(const float* __restrict__ k) {
  const int i = blockIdx.x * 256 + threadIdx.x;    // over 262144 float4
  float4 v = ((const float4*)k)[i];
  ushort4 hf, hb, lb;
  hf.x = f2h(v.x); hb.x = f2bf(v.x); lb.x = f2bf(v.x - bf2f(hb.x));
  hf.y = f2h(v.y); hb.y = f2bf(v.y); lb.y = f2bf(v.y - bf2f(hb.y));
  hf.z = f2h(v.z); hb.z = f2bf(v.z); lb.z = f2bf(v.z - bf2f(hb.z));
  hf.w = f2h(v.w); hb.w = f2bf(v.w); lb.w = f2bf(v.w - bf2f(hb.w));
  ((ushort4*)g_kh)[i]  = hf;
  ((ushort4*)g_kbh)[i] = hb;
  ((ushort4*)g_kbl)[i] = lb;
}

// ---------------------------------------------------------------- pass 1: fp16 VQ kernel
// Swapped operands: mfma(A=k, B=x); lane holds 4 codes x 4 rows.
// Running top-2 in WAVE-PRIVATE LDS; barrier-free main loop; manual ks-unroll-2
// (two ak loads in flight; second half's bx loads overlap first half's MFMAs).
__global__ __launch_bounds__(1024, 8) void vq_mfma(const float* __restrict__ x) {
  __shared__ unsigned short x_s[R * XS_ROW];   // 65536 B, fp16, swizzled
  __shared__ float  cand_d1[16][R];            // doubles as px2 during staging
  __shared__ float  cand_d2[16][R];
  __shared__ int    cand_i[16][R];
  __shared__ float  x2s[R];
  __shared__ double pnred[32];

  const int tid = threadIdx.x;
  const int wv = tid >> 6, lane = tid & 63;
  const int g = lane >> 4, i16 = lane & 15;
  const int rows0 = blockIdx.x * R;
  const int n = rows0 >> 13, t0 = rows0 & (TLEN - 1);
  const int swz = (i16 & 7) << 3;

  // ---- staging: transpose + fp16 convert + x2 + prenorm (f32 partials) ----
  {
    float sv = 0.f, px = 0.f;
    const size_t xb = ((size_t)(n * WEMB + wv * 32)) * TLEN + (size_t)(t0 + lane);
    const int wsz = (lane & 7) << 3;
#pragma unroll
    for (int jg = 0; jg < 4; ++jg) {
      half8 h8;
#pragma unroll
      for (int j = 0; j < 8; ++j) {
        const float v = __builtin_nontemporal_load(&x[xb + (size_t)(jg * 8 + j) * TLEN]);
        h8[j] = (_Float16)v;
        px = fmaf(v, v, px);
        sv += v;
      }
      const int col = wv * 32 + jg * 8;
      *(half8*)&x_s[lane * XS_ROW + (col ^ wsz)] = h8;
    }
    cand_d1[wv][lane] = px;     // per-lane x2 slice
    float svr = sv, pxr = px;
#pragma unroll
    for (int m = 1; m < 64; m <<= 1) { svr += __shfl_xor(svr, m); pxr += __shfl_xor(pxr, m); }
    if (lane == 0) { pnred[wv] = (double)svr; pnred[16 + wv] = (double)pxr; }
  }
  __syncthreads();
  if (tid < R) {
    float t = 0.f;
#pragma unroll
    for (int w16 = 0; w16 < 16; ++w16) t += cand_d1[w16][tid];
    x2s[tid] = t;
  }
  if (tid == 0) {
    double a = 0, b = 0;
#pragma unroll
    for (int w16 = 0; w16 < 16; ++w16) { a += pnred[w16]; b += pnred[16 + w16]; }
    g_pnp[2 * blockIdx.x] = a; g_pnp[2 * blockIdx.x + 1] = b;
  }
  __syncthreads();

  // ---- init wave-private running top-2 state (each wave owns cand[wv][*]) ----
  cand_d1[wv][lane] = 3.4e38f;
  cand_d2[wv][lane] = 3.4e38f;
  cand_i [wv][lane] = 0x7FFFFFFF;

  // ---- main loop: 8 chunks x 256 codes; wave strip = 16 codes; barrier-free ----
  for (int cc = 0; cc < 8; ++cc) {
    const int cb = cc * 256 + wv * 16;
    const unsigned short* kp = g_kh + ((size_t)(cb + i16)) * WEMB + (size_t)(g * 8);
    f32x4 acc[4];
#pragma unroll
    for (int mt = 0; mt < 4; ++mt) acc[mt] = (f32x4){0.f, 0.f, 0.f, 0.f};

#pragma unroll 1
    for (int kp2 = 0; kp2 < 8; ++kp2) {
      const int ks0 = 2 * kp2, ks1 = 2 * kp2 + 1;
      const half8 ak0 = *(const half8*)&kp[ks0 * 32];
      const half8 ak1 = *(const half8*)&kp[ks1 * 32];
#pragma unroll
      for (int mt = 0; mt < 4; ++mt) {
        const half8 bx = *(const half8*)&x_s[(mt * 16 + i16) * XS_ROW + ((ks0 * 32 + g * 8) ^ swz)];
        acc[mt] = __builtin_amdgcn_mfma_f32_16x16x32_f16(ak0, bx, acc[mt], 0, 0, 0);
      }
#pragma unroll
      for (int mt = 0; mt < 4; ++mt) {
        const half8 bx = *(const half8*)&x_s[(mt * 16 + i16) * XS_ROW + ((ks1 * 32 + g * 8) ^ swz)];
        acc[mt] = __builtin_amdgcn_mfma_f32_16x16x32_f16(ak1, bx, acc[mt], 0, 0, 0);
      }
    }

    float k2r[4];
#pragma unroll
    for (int r = 0; r < 4; ++r) k2r[r] = g_k2[cb + g * 4 + r];
#pragma unroll
    for (int mt = 0; mt < 4; ++mt) {
      const int row = mt * 16 + i16;
      const float xx = x2s[row];
      float e1 = 3.4e38f, e2 = 3.4e38f; int ei = 0x7FFFFFFF;
#pragma unroll
      for (int r = 0; r < 4; ++r) {
        const float d = fmaf(-2.f, acc[mt][r], xx) + k2r[r];
        const int code = cb + g * 4 + r;       // ascending per lane
        if (d < e1) { e2 = e1; e1 = d; ei = code; } else e2 = fminf(e2, d);
      }
      // butterfly over g (xor 16, 32); codes ascend with g -> tie keeps lower idx
#pragma unroll
      for (int m = 16; m <= 32; m <<= 1) {
        const float o1 = __shfl_xor(e1, m);
        const float o2 = __shfl_xor(e2, m);
        const int   oi = __shfl_xor(ei, m);
        if (o1 < e1)      { e2 = fminf(e1, o2); e1 = o1; ei = oi; }
        else if (o1 > e1) { e2 = fminf(e2, o1); }
        else              { e2 = fminf(e2, o2); if (oi < ei) ei = oi; }
      }
      if (g == 0) {      // wave-private LDS merge, no barrier needed
        const float c1 = cand_d1[wv][row], c2 = cand_d2[wv][row];
        const int ci = cand_i[wv][row];
        if (e1 < c1)      { cand_d2[wv][row] = fminf(c1, e2); cand_d1[wv][row] = e1; cand_i[wv][row] = ei; }
        else if (e1 > c1) { cand_d2[wv][row] = fminf(c2, e1); }
        else              { cand_d2[wv][row] = fminf(c2, e2); if (ei < ci) cand_i[wv][row] = ei; }
      }
    }
  }

  // ---- final cross-wave merge ----
  __syncthreads();
  if (tid < R) {
    float m1 = 3.4e38f, m2 = 3.4e38f; int mi = 0x7FFFFFFF;
#pragma unroll
    for (int w16 = 0; w16 < 16; ++w16) {
      const float c1 = cand_d1[w16][tid], c2 = cand_d2[w16][tid];
      const int ci = cand_i[w16][tid];
      if (c1 < m1)      { m2 = fminf(m1, c2); m1 = c1; mi = ci; }
      else if (c1 > m1) { m2 = fminf(m2, c1); }
      else              { m2 = fminf(m2, c2); if (ci < mi) mi = ci; }
    }
    const int grow = rows0 + tid;
    g_idx[grow] = mi;
    if (m2 - m1 < MARGIN1) {
      const int pos = atomicAdd(&g_nfix, 1);
      if (pos < FIX_CAP) g_list[pos] = grow;
    }
    double fs = (double)m1;
#pragma unroll
    for (int m = 1; m < 64; m <<= 1) fs += __shfl_xor(fs, m);
    if (tid == 0) g_fitp[blockIdx.x] = fs;
  }
}

// ---------------------------------------------------------------- pass 2: bf16-3prod rescan of flagged rows
__global__ __launch_bounds__(1024, 1) void fix1_mfma(const float* __restrict__ x) {
  __shared__ short  x_s[64 * 1024];        // 128 KB bf16 hi/lo, swizzled
  __shared__ float  cand_d1[16][64];
  __shared__ float  cand_d2[16][64];
  __shared__ int    cand_i[16][64];
  __shared__ float  x2s[64];
  __shared__ float  rd1[64], rd2[64];
  __shared__ int    ri1[64];

  const int tid = threadIdx.x;
  const int wv = tid >> 6, lane = tid & 63;
  const int g = lane >> 4, i16 = lane & 15;
  const int swz = (i16 & 7) << 3;
  const int nfix = g_nfix < FIX_CAP ? g_nfix : FIX_CAP;

  for (int base = blockIdx.x * 64; base < nfix; base += gridDim.x * 64) {
    __syncthreads();
    if (tid < 64) { rd1[tid] = 3.4e38f; rd2[tid] = 3.4e38f; ri1[tid] = 0; }
    {
      const int rl = tid >> 4;
      int e = base + rl; if (e >= nfix) e = nfix - 1;
      const int row = g_list[e];
      const int n = row >> 13, t = row & (TLEN - 1);
      const int ks = tid & 15;
      const int wsz = (rl & 7) << 3;
      float px = 0.f;
#pragma unroll
      for (int jg = 0; jg < 4; ++jg) {
        short8 h8, l8;
#pragma unroll
        for (int j = 0; j < 8; ++j) {
          const int w = ks * 32 + jg * 8 + j;
          const float v = x[((size_t)(n * WEMB + w)) * TLEN + (size_t)t];
          const unsigned short h = f2bf(v);
          const unsigned short lo = f2bf(v - bf2f(h));
          h8[j] = (short)h; l8[j] = (short)lo;
          px = fmaf(v, v, px);
        }
        const int colh = ks * 64 + jg * 8;
        *(short8*)&x_s[rl * 1024 + (colh ^ wsz)] = h8;
        *(short8*)&x_s[rl * 1024 + ((colh + 32) ^ wsz)] = l8;
      }
#pragma unroll
      for (int m = 1; m < 16; m <<= 1) px += __shfl_xor(px, m);
      if (ks == 0) x2s[rl] = px;
    }
    __syncthreads();

    for (int cc = 0; cc < 4; ++cc) {
      const int cb = cc * 512 + wv * 32;
      f32x4 acc[4][2];
#pragma unroll
      for (int mt = 0; mt < 4; ++mt)
#pragma unroll
        for (int nt = 0; nt < 2; ++nt) acc[mt][nt] = (f32x4){0.f, 0.f, 0.f, 0.f};

#pragma unroll 1
      for (int ks = 0; ks < 16; ++ks) {
        short8 bh[2], bl[2];
#pragma unroll
        for (int nt = 0; nt < 2; ++nt) {
          const size_t bidx = ((size_t)(cb + nt * 16 + i16)) * WEMB + (size_t)(ks * 32 + g * 8);
          bh[nt] = *(const short8*)&g_kbh[bidx];
          bl[nt] = *(const short8*)&g_kbl[bidx];
        }
#pragma unroll
        for (int mt = 0; mt < 4; ++mt) {
          const int rbase = (mt * 16 + i16) * 1024 + (ks * 64);
          const short8 ah = *(const short8*)&x_s[rbase + ((g * 8) ^ swz)];
          const short8 al = *(const short8*)&x_s[rbase + ((32 + g * 8) ^ swz)];
          acc[mt][0] = __builtin_amdgcn_mfma_f32_16x16x32_bf16(ah, bh[0], acc[mt][0], 0, 0, 0);
          acc[mt][1] = __builtin_amdgcn_mfma_f32_16x16x32_bf16(ah, bh[1], acc[mt][1], 0, 0, 0);
          acc[mt][0] = __builtin_amdgcn_mfma_f32_16x16x32_bf16(ah, bl[0], acc[mt][0], 0, 0, 0);
          acc[mt][1] = __builtin_amdgcn_mfma_f32_16x16x32_bf16(ah, bl[1], acc[mt][1], 0, 0, 0);
          acc[mt][0] = __builtin_amdgcn_mfma_f32_16x16x32_bf16(al, bh[0], acc[mt][0], 0, 0, 0);
          acc[mt][1] = __builtin_amdgcn_mfma_f32_16x16x32_bf16(al, bh[1], acc[mt][1], 0, 0, 0);
        }
      }

      float k2v[2];
#pragma unroll
      for (int nt = 0; nt < 2; ++nt) k2v[nt] = g_k2[cb + nt * 16 + i16];
#pragma unroll
      for (int mt = 0; mt < 4; ++mt) {
#pragma unroll
        for (int rr = 0; rr < 4; ++rr) {
          const int row = mt * 16 + g * 4 + rr;
          const float xx = x2s[row];
          float e1 = 3.4e38f, e2 = 3.4e38f; int ei = 0x7FFFFFFF;
#pragma unroll
          for (int nt = 0; nt < 2; ++nt) {
            const float d = fmaf(-2.f, acc[mt][nt][rr], xx) + k2v[nt];
            const int code = cb + nt * 16 + i16;
            if (d < e1) { e2 = e1; e1 = d; ei = code; } else e2 = fminf(e2, d);
          }
#pragma unroll
          for (int m = 1; m < 16; m <<= 1) {
            const float o1 = __shfl_xor(e1, m);
            const float o2 = __shfl_xor(e2, m);
            const int   oi = __shfl_xor(ei, m);
            if (o1 < e1)      { e2 = fminf(e1, o2); e1 = o1; ei = oi; }
            else if (o1 > e1) { e2 = fminf(e2, o1); }
            else              { e2 = e1; if (oi < ei) ei = oi; }
          }
          if (i16 == 0) { cand_d1[wv][row] = e1; cand_d2[wv][row] = e2; cand_i[wv][row] = ei; }
        }
      }
      __syncthreads();
      if (tid < 64) {
        float m1 = rd1[tid], m2 = rd2[tid]; int mi = ri1[tid];
#pragma unroll
        for (int w16 = 0; w16 < 16; ++w16) {
          const float c1 = cand_d1[w16][tid], c2 = cand_d2[w16][tid];
          const int ci = cand_i[w16][tid];
          if (c1 < m1)      { m2 = fminf(m1, c2); m1 = c1; mi = ci; }
          else if (c1 > m1) { m2 = fminf(m2, c1); }
          else              { m2 = fminf(m2, c2); if (ci < mi) mi = ci; }
        }
        rd1[tid] = m1; rd2[tid] = m2; ri1[tid] = mi;
      }
      __syncthreads();
    }

    if (tid < 64) {
      const int e = base + tid;
      if (e < nfix) {
        const int row = g_list[e];
        g_idx[row] = ri1[tid];
        if (rd2[tid] - rd1[tid] < MARGIN2) {
          const int p = atomicAdd(&g_nfix2, 1);
          if (p < FIX2_CAP) g_list2[p] = row;
        }
      }
    }
  }
}

// ---------------------------------------------------------------- pass 3: exact f64 scan of list2
__global__ __launch_bounds__(256) void fix2_kernel(const float* __restrict__ x,
                                                   const float* __restrict__ k) {
  __shared__ float  xr[WEMB];
  __shared__ double rbd[4];
  __shared__ int    rbi[4];
  const int nf = g_nfix2 < FIX2_CAP ? g_nfix2 : FIX2_CAP;
  const int tid = threadIdx.x, lane = tid & 63, wv = tid >> 6;
  for (int e = blockIdx.x; e < nf; e += gridDim.x) {
    const int row = g_list2[e];
    const int n = row >> 13, t = row & (TLEN - 1);
    for (int w = tid; w < WEMB; w += 256)
      xr[w] = x[(size_t)(n * WEMB + w) * TLEN + (size_t)t];
    __syncthreads();
    double bd = 1e300; int bi = 0x7FFFFFFF;
    for (int p = 0; p < 8; ++p) {
      const int c = tid + 256 * p;
      const float* kc = k + (size_t)c * WEMB;
      double d = 0.0;
      for (int w = 0; w < WEMB; ++w) {
        const double df = (double)xr[w] - (double)kc[w];
        d = fma(df, df, d);
      }
      if (d < bd || (d == bd && c < bi)) { bd = d; bi = c; }
    }
#pragma unroll
    for (int m = 1; m < 64; m <<= 1) {
      const double od = __shfl_xor(bd, m);
      const int    oi = __shfl_xor(bi, m);
      if (od < bd || (od == bd && oi < bi)) { bd = od; bi = oi; }
    }
    if (lane == 0) { rbd[wv] = bd; rbi[wv] = bi; }
    __syncthreads();
    if (tid == 0) {
      double fb = rbd[0]; int fi = rbi[0];
#pragma unroll
      for (int v = 1; v < 4; ++v)
        if (rbd[v] < fb || (rbd[v] == fb && rbi[v] < fi)) { fb = rbd[v]; fi = rbi[v]; }
      g_idx[row] = fi;
    }
    __syncthreads();
  }
}

// ---------------------------------------------------------------- x_l write (f32, NT)
__global__ __launch_bounds__(256) void xl_kernel(float* __restrict__ out) {
  const int i = blockIdx.x * 256 + threadIdx.x;
  if (i < NTROWS) __builtin_nontemporal_store((float)g_idx[i], &out[i]);
}

// ---------------------------------------------------------------- x_q write (LDS transpose, NT stores)
__global__ __launch_bounds__(256) void xq_kernel(const float* __restrict__ k,
                                                 float* __restrict__ out) {
  __shared__ float tile[64][257];
  __shared__ int idxs[64];
  const int tb = blockIdx.x;
  const int n = tb >> 7, t0 = (tb & 127) << 6;
  const int tid = threadIdx.x, lane = tid & 63;
  if (tid < 64) idxs[tid] = g_idx[n * TLEN + t0 + tid];
  __syncthreads();
  for (int half = 0; half < 2; ++half) {
    const int w0 = half * 256;
    if (half) __syncthreads();
#pragma unroll 4
    for (int it = 0; it < 16; ++it) {
      const int r = (tid >> 6) + 4 * it;
      const float4 v = *(const float4*)&k[(size_t)idxs[r] * WEMB + (size_t)(w0 + lane * 4)];
      tile[r][lane * 4 + 0] = v.x; tile[r][lane * 4 + 1] = v.y;
      tile[r][lane * 4 + 2] = v.z; tile[r][lane * 4 + 3] = v.w;
    }
    __syncthreads();
#pragma unroll 4
    for (int it = 0; it < 64; ++it) {
      const int wl = it * 4 + (tid >> 6);
      __builtin_nontemporal_store(tile[lane][wl],
          &out[XQ_OFF + ((size_t)(n * WEMB + w0 + wl)) * TLEN + (size_t)(t0 + lane)]);
    }
  }
}

// ---------------------------------------------------------------- final scalars (f32)
__global__ __launch_bounds__(256) void fin_kernel(float* __restrict__ out) {
  const int tid = threadIdx.x;
  double fs = 0, s = 0, s2 = 0;
  for (int i = tid; i < 2048; i += 256) {
    fs += g_fitp[i];
    s  += g_pnp[2 * i];
    s2 += g_pnp[2 * i + 1];
  }
#pragma unroll
  for (int m = 1; m < 64; m <<= 1) {
    fs += __shfl_xor(fs, m); s += __shfl_xor(s, m); s2 += __shfl_xor(s2, m);
  }
  __shared__ double red[12];
  const int wv = tid >> 6, lane = tid & 63;
  if (lane == 0) { red[wv] = fs; red[4 + wv] = s; red[8 + wv] = s2; }
  __syncthreads();
  if (tid == 0) {
    const double F  = red[0] + red[1] + red[2] + red[3];
    const double S  = red[4] + red[5] + red[6] + red[7];
    const double S2 = red[8] + red[9] + red[10] + red[11];
    const double nel = (double)NTROWS * (double)WEMB;
    const double mean = S / nel;
    double var = S2 / nel - mean * mean;
    if (var < 0) var = 0;
    out[SC_OFF + 0] = (float)(F / nel);      // commit_loss
    out[SC_OFF + 1] = (float)(F / NTROWS);   // fit
    out[SC_OFF + 2] = (float)sqrt(var);      // prenorm
  }
}

extern "C" void kernel_launch(void* const* d_in, const int* in_sizes, int n_in,
                              void* d_out, int out_size, void* d_ws, size_t ws_size,
                              hipStream_t stream) {
  const float* x = (const float*)d_in[0];
  const float* k = (const float*)d_in[1];
  float* out = (float*)d_out;
  (void)d_ws; (void)ws_size; (void)in_sizes; (void)n_in; (void)out_size;

  hipLaunchKernelGGL(zero_kernel, dim3(1), dim3(1), 0, stream);
  hipLaunchKernelGGL(k2_kernel, dim3(KBINS / 4), dim3(256), 0, stream, k);
  hipLaunchKernelGGL(kprep_kernel, dim3(1024), dim3(256), 0, stream, k);
  hipLaunchKernelGGL(vq_mfma, dim3(NTROWS / R), dim3(1024), 0, stream, x);
  hipLaunchKernelGGL(fix1_mfma, dim3(512), dim3(1024), 0, stream, x);
  hipLaunchKernelGGL(fix2_kernel, dim3(1024), dim3(256), 0, stream, x, k);
  hipLaunchKernelGGL(xl_kernel, dim3(NTROWS / 256), dim3(256), 0, stream, out);
  hipLaunchKernelGGL(xq_kernel, dim3(2048), dim3(256), 0, stream, k, out);
  hipLaunchKernelGGL(fin_kernel, dim3(1), dim3(256), 0, stream, out);
}